// Round 16
// baseline (216.716 us; speedup 1.0000x reference)
//
#include <hip/hip_runtime.h>
#include <hip/hip_fp16.h>
#include <stdint.h>

#define T_LEN 262144
#define S 64
#define SP1 65
#define NCT 131072              // composed-step domain; ct in [0,131070] valid

// forward (composed): L=16 composed outputs + W=4 composed warm-up (=8 real)
#define L_C 16
#define W_C 4
#define NSTEP (L_C + W_C)       // 20, fully unrolled
#define C_FWD (NCT / L_C)       // 8192 chains -> 2048 blocks of 256

// backtrack: wave-per-window, 16 t-outputs (8 composed) per window
#define NW2 (T_LEN / 16)        // 16384 windows -> 4096 blocks of 256

template <int CTRL>
__device__ __forceinline__ float dpp_fmax_step(float v) {
    int t = __builtin_amdgcn_update_dpp(__float_as_int(v), __float_as_int(v),
                                        CTRL, 0xf, 0xf, false);
    return fmaxf(__int_as_float(t), v);
}
template <int CTRL>
__device__ __forceinline__ unsigned int dpp_umin_step(unsigned int v) {
    unsigned int t = (unsigned int)__builtin_amdgcn_update_dpp(
        (int)v, (int)v, CTRL, 0xf, 0xf, false);
    return t < v ? t : v;
}
__device__ __forceinline__ float readlane_f(float v, int lane) {
    return __int_as_float(__builtin_amdgcn_readlane(__float_as_int(v), lane));
}
// packed argmax key: all scores < 0 -> u32-min on raw bits == float-max;
// low 6 bits carry j; tie-break = smaller j.
__device__ __forceinline__ unsigned int pack_key(float a, int j) {
    return (__float_as_uint(a) & 0xFFFFFFC0u) | (unsigned)j;
}
// full 64-lane packed-key u32-min (result broadcast from lane 63)
__device__ __forceinline__ unsigned int wave_umin(unsigned int key) {
    key = dpp_umin_step<0x111>(key);
    key = dpp_umin_step<0x112>(key);
    key = dpp_umin_step<0x114>(key);
    key = dpp_umin_step<0x118>(key);
    key = dpp_umin_step<0x142>(key);
    key = dpp_umin_step<0x143>(key);
    return (unsigned int)__builtin_amdgcn_readlane((int)key, 63);
}

// k0: build the 128 composed matrices M2^r[i][j] = max_k(trans[i][k] +
// ll_r[k] + trans[k][j]) (col-major to global, 2 MB -> L2) and the exact
// per-r pruning bound Mc2[r][j] = min_i(rowmin2_i - M2[i][j]) <= 0.
// One block per r; wave handles 4 i-rows, lane = j.
__global__ __launch_bounds__(1024) void k0_m2(
    const float* __restrict__ trans, const float* __restrict__ ll,
    float* __restrict__ wsM2col, float* __restrict__ wsMc2,
    float* __restrict__ out_score) {
    __shared__ float sR[S * S];   // [i<<6|k] = trans[i][k]
    __shared__ float sC[S * S];   // [k<<6|j] = trans[k][j]  (same values)
    __shared__ float sv[S];       // ll[r][k]
    __shared__ float sM2[S * S];  // [i<<6|j]
    __shared__ float srm[S];
    const int r = blockIdx.x, tid = threadIdx.x;
    const int lane = tid & 63, wv = tid >> 6;
    for (int k = tid; k < S * S; k += 1024) {
        float v = trans[(k >> 6) * SP1 + (k & 63)];
        sR[k] = v;                 // row-major
        sC[k] = v;                 // identical layout; named for access role
    }
    if (tid < S) sv[tid] = ll[r * S + tid];
    __syncthreads();
    #pragma unroll
    for (int ii = 0; ii < 4; ++ii) {          // wave's 4 i-rows
        int i = wv * 4 + ii;
        float m = -3.0e38f;
        for (int k = 0; k < S; ++k) {
            float tik = sR[(i << 6) | k] + sv[k];  // broadcast LDS read
            m = fmaxf(m, tik + sC[(k << 6) | lane]);
        }
        sM2[(i << 6) | lane] = m;
    }
    __syncthreads();
    if (tid < S) {
        float rm = 3.0e38f;
        for (int j = 0; j < S; ++j) rm = fminf(rm, sM2[(tid << 6) | j]);
        srm[tid] = rm;
    }
    __syncthreads();
    if (tid < S) {
        float mc = 3.0e38f;
        for (int i = 0; i < S; ++i) mc = fminf(mc, srm[i] - sM2[(i << 6) | tid]);
        wsMc2[r * S + tid] = mc;
    }
    for (int idx = tid; idx < S * S; idx += 1024) {   // col-major out
        int j = idx >> 6, i = idx & 63;
        wsM2col[(r << 12) | idx] = sM2[(i << 6) | j];
    }
    if (r == 0 && tid == 0) out_score[0] = 0.0f;
}

// k1: composed forward chain, one chain per wave, 4/block, 8 blocks/CU.
// Composed step ct: delta_{2ct+2}[i] = max_j(M2^{rE}[i][j] + llO[j] + d[j]),
// rE = rolls[2ct+2], llO = ll[rolls[2ct+1]]. Fully unrolled straight line;
// survivor columns gathered from L2 (M2 col-major); eager-4 truncated via
// exact Mc2 bound; fp16 ll in LDS; bp (state at 2ct) packed 4/dword in
// registers, burst-stored. Last chain also runs the final odd real step
// (t = T-1) brute-force -> wsFinal + bpF[ i ] = argmax_j.
__global__ __launch_bounds__(256, 8) void k1_forward(
    const int* __restrict__ rolls, const float* __restrict__ trans,
    const float* __restrict__ ll, const float* __restrict__ wsMc2,
    const float* __restrict__ wsM2col, unsigned int* __restrict__ bp4,
    int* __restrict__ wsFinal, unsigned char* __restrict__ bpF) {
    __shared__ __half sll[128 * S];   // [r<<6|i] = ll[r][i], 16 KB
    const int tid = threadIdx.x;
    const int lane = tid & 63;
    const int wv = tid >> 6;

    for (int k = tid; k < 128 * S; k += 256)
        sll[k] = __float2half(ll[k]);
    __syncthreads();

    const int c = blockIdx.x * 4 + wv;
    const int ct0 = c * L_C - W_C;

    // per-chunk rolls: lane u holds the pair (odd, even) rolls of ct0+u
    int ci = ct0 + lane;
    int vrO = rolls[min(max(2 * ci + 1, 0), T_LEN - 1)];
    int vrE = rolls[min(max(2 * ci + 2, 0), T_LEN - 1)];

    float delta = 0.0f;  // arbitrary; warm-up coalesces (additive const)
    unsigned int pk[4];
    float dsave = 0.0f;

    // pipelines: ll (LDS) and Mc2 (global) prefetched one step ahead
    int rO0 = __builtin_amdgcn_readlane(vrO, 0);
    int rE0 = __builtin_amdgcn_readlane(vrE, 0);
    float ll_cur = __half2float(sll[(rO0 << 6) | lane]);
    float mc_cur = wsMc2[(rE0 << 6) | lane];

    #pragma unroll
    for (int st = 0; st < NSTEP; ++st) {
        int rO_n = __builtin_amdgcn_readlane(vrO, st + 1);   // lane 20 valid
        int rE_n = __builtin_amdgcn_readlane(vrE, st + 1);
        float ll_nxt = __half2float(sll[(rO_n << 6) | lane]);
        float mc_nxt = wsMc2[(rE_n << 6) | lane];
        int rE = __builtin_amdgcn_readlane(vrE, st);

        if (st == NSTEP - 1) dsave = delta;  // pre-junk delta for last chain

        float cvec = delta + ll_cur;  // < 0 always

        float mxc = cvec;             // exact wave max
        mxc = dpp_fmax_step<0x111>(mxc);
        mxc = dpp_fmax_step<0x112>(mxc);
        mxc = dpp_fmax_step<0x114>(mxc);
        mxc = dpp_fmax_step<0x118>(mxc);
        mxc = dpp_fmax_step<0x142>(mxc);
        mxc = dpp_fmax_step<0x143>(mxc);
        float cmax = readlane_f(mxc, 63);

        float thr = cmax + mc_cur;    // exact necessity for winners
        unsigned long long m0 = __ballot(cvec >= thr);

        int j0 = __ffsll(m0) - 1;
        unsigned long long m1 = m0 & (m0 - 1);
        int j1 = m1 ? (__ffsll(m1) - 1) : j0;
        unsigned long long m2 = m1 & (m1 - 1);
        int j2 = m2 ? (__ffsll(m2) - 1) : j0;
        unsigned long long m3 = m2 & (m2 - 1);
        int j3 = m3 ? (__ffsll(m3) - 1) : j0;

        const float* base = wsM2col + ((size_t)rE << 12);
        float a0 = base[(j0 << 6) | lane] + readlane_f(cvec, j0);
        float a1 = base[(j1 << 6) | lane] + readlane_f(cvec, j1);
        float a2 = base[(j2 << 6) | lane] + readlane_f(cvec, j2);
        float a3 = base[(j3 << 6) | lane] + readlane_f(cvec, j3);

        unsigned int m = min(min(pack_key(a0, j0), pack_key(a1, j1)),
                             min(pack_key(a2, j2), pack_key(a3, j3)));

        delta = __uint_as_float(m & 0xFFFFFFC0u);

        if (st >= W_C) {  // compile-time (unrolled): record bp byte
            int q = (st - W_C) >> 2, u = (st - W_C) & 3;
            if (u == 0) pk[q] = (m & 63u);
            else        pk[q] |= (m & 63u) << (8 * u);
        }
        ll_cur = ll_nxt;
        mc_cur = mc_nxt;
    }

    const int qb = c * 4;
    #pragma unroll
    for (int q = 0; q < 4; ++q)
        bp4[(unsigned)((qb + q) << 6) | (unsigned)lane] = pk[q];

    if (c == C_FWD - 1) {
        // final real step t = T-1 (odd): deltaF[i] = max_j(trans[i][j] +
        // ll_{T-1}[j] + d_{T-2}[j]); d_{T-2} = dsave (delta before junk step)
        int rF = rolls[T_LEN - 1];
        float cvF = dsave + __half2float(sll[(rF << 6) | lane]);
        unsigned int mbest = 0xFFFFFFFFu;
        for (int j = 0; j < S; ++j) {
            float a = trans[lane * SP1 + j] + readlane_f(cvF, j);
            mbest = min(mbest, pack_key(a, j));
        }
        bpF[lane] = (unsigned char)(mbest & 63u);
        float deltaF = __uint_as_float(mbest & 0xFFFFFFC0u);
        unsigned int kall = wave_umin(pack_key(deltaF, lane));
        if (lane == 0)
            *wsFinal = (int)(kall & 63u);
    }
}

// k2: wave-per-window (16 t-outputs). Composed chase for even states
// (exact-seeded near the tail via bpF), wave-parallel 64-argmax recovery of
// odd states, path write, fused exact scoring (fp32 tables).
__global__ __launch_bounds__(256) void k2_backtrack(
    const unsigned int* __restrict__ bp4, const int* __restrict__ wsFinal,
    const unsigned char* __restrict__ bpF, const int* __restrict__ rolls,
    const float* __restrict__ trans, const float* __restrict__ ll,
    float* __restrict__ out_path, float* __restrict__ out_score) {
    __shared__ float sR[S * S];   // [i<<6|k] = trans[i][k]
    __shared__ float sC[S * S];   // [j<<6|k] = trans[k][j]
    __shared__ int swin[4][18];   // window states by t-offset 0..16
    __shared__ float spart[4];
    const int tid = threadIdx.x;
    const int lane = tid & 63;
    const int wv = tid >> 6;

    for (int k = tid; k < S * S; k += 256) {
        int i = k >> 6, j = k & 63;
        float v = trans[i * SP1 + j];
        sR[(i << 6) | j] = v;
        sC[(j << 6) | i] = v;     // one-time conflicted write
    }
    __syncthreads();

    const int w = blockIdx.x * 4 + wv;   // window id
    const int tlo = w * 16;
    const int ctlo = w * 8;

    int cte, s;
    if (ctlo + 16 >= NCT) {              // tail: exact seed at t = T-2
        cte = NCT - 1;                   // 131071
        s = (int)bpF[*wsFinal];          // s_{T-2}
    } else {
        cte = ctlo + 16;
        s = 0;                           // arbitrary; chase coalesces
    }
    if (cte <= ctlo + 8 && lane == 0)
        swin[wv][2 * (cte - ctlo)] = s;
    for (int ct = cte - 1; ct >= ctlo; --ct) {   // reads ct <= 131070 only
        unsigned int wd = bp4[((unsigned)(ct >> 2) << 6) | (unsigned)s];
        s = (int)((wd >> ((ct & 3) << 3)) & 63u);
        if (ct <= ctlo + 8 && lane == 0)
            swin[wv][2 * (ct - ctlo)] = s;
    }

    // odd-state recovery: s_{2ct+1} = argmax_k(trans[i][k] + ll_rE[k] +
    // trans[k][j]), i = s_{2ct+2}, j = s_{2ct}, rE = rolls[2ct+2]
    int rq = rolls[min(2 * (ctlo + lane) + 2, T_LEN - 1)];
    #pragma unroll
    for (int q = 0; q < 8; ++q) {
        int ct = ctlo + q;
        int i = swin[wv][2 * q + 2];
        int j = swin[wv][2 * q];
        int sodd;
        if (ct >= NCT - 1) {             // t = T-1: the exact final state
            sodd = *wsFinal;
        } else {
            int r = __builtin_amdgcn_readlane(rq, q);
            float val = sR[(i << 6) | lane] + ll[(r << 6) + lane] +
                        sC[(j << 6) | lane];
            unsigned int kall = wave_umin(pack_key(val, lane));
            sodd = (int)(kall & 63u);
        }
        if (lane == 0) swin[wv][2 * q + 1] = sodd;
    }

    // path write: out[T-1-t] = s_t for t in [tlo, tlo+16)
    if (lane < 16)
        out_path[T_LEN - 1 - (tlo + lane)] = (float)swin[wv][lane];

    // exact score terms: t in [tlo+1, tlo+16] (clamped to T-1)
    float term = 0.0f;
    if (lane < 16) {
        int t = tlo + 1 + lane;
        if (t <= T_LEN - 1) {
            int sp = swin[wv][lane];
            int st_ = swin[wv][lane + 1];
            term = trans[st_ * SP1 + sp] + ll[rolls[t] * S + sp];
        }
    } else if (lane == 16 && w == 0) {
        int s0 = swin[wv][0];
        term = trans[s0 * SP1 + S] + ll[rolls[0] * S + s0];
    }
    for (int off = 32; off; off >>= 1)
        term += __shfl_xor(term, off);
    if (lane == 0) spart[wv] = term;
    __syncthreads();
    if (tid == 0)
        atomicAdd(out_score, (spart[0] + spart[1]) + (spart[2] + spart[3]));
}

extern "C" void kernel_launch(void* const* d_in, const int* in_sizes, int n_in,
                              void* d_out, int out_size, void* d_ws, size_t ws_size,
                              hipStream_t stream) {
    const int* rolls = (const int*)d_in[0];
    const float* trans = (const float*)d_in[1];   // (64, 65)
    const float* ll = (const float*)d_in[2];      // (128, 64)
    float* out = (float*)d_out;                   // [0..T): path (reverse), [T]: score
    char* ws = (char*)d_ws;
    int* wsFinal = (int*)(ws + 8);
    unsigned char* bpF = (unsigned char*)(ws + 128);          // 64 B
    float* wsMc2 = (float*)(ws + 4096);                       // 32 KB
    float* wsM2col = (float*)(ws + 64 * 1024);                // 2 MB
    unsigned int* bp4 = (unsigned int*)(ws + 4 * 1024 * 1024); // 8 MB

    k0_m2<<<128, 1024, 0, stream>>>(trans, ll, wsM2col, wsMc2, out + T_LEN);
    k1_forward<<<C_FWD / 4, 256, 0, stream>>>(rolls, trans, ll, wsMc2, wsM2col,
                                              bp4, wsFinal, bpF);
    k2_backtrack<<<NW2 / 4, 256, 0, stream>>>(bp4, wsFinal, bpF, rolls, trans,
                                              ll, out, out + T_LEN);
}

// Round 17
// 110.006 us; speedup vs baseline: 1.9700x; 1.9700x over previous
//
#include <hip/hip_runtime.h>
#include <hip/hip_fp16.h>
#include <stdint.h>

#define T_LEN 262144
#define S 64
#define SP1 65

// forward: L=32 outputs + W=4 warm-up, ONE chain per wave (TLP > ILP:
// R10 measured 2 chains/wave at half the waves runs 2x slower; R16 measured
// composed 2-step squaring loses on constant factors).
// 8192 chains -> 2048 blocks of 256.
#define L_FWD 32
#define W_FWD 4
#define C_FWD (T_LEN / L_FWD)   // 8192

// backtrack: one THREAD per window. LB=8 outputs, VB=8 warm chase.
#define LB2 8
#define VB2 8
#define NW (T_LEN / LB2)        // 32768 windows -> 128 blocks of 256
#define PITCH (LB2 + 2)

// DPP cumulative-fmax step (old = own value, bound_ctrl=false). After
// shr1,2,4,8 + bcast15 + bcast31, lane 63 holds the wave-wide max.
template <int CTRL>
__device__ __forceinline__ float dpp_fmax_step(float v) {
    int t = __builtin_amdgcn_update_dpp(__float_as_int(v), __float_as_int(v),
                                        CTRL, 0xf, 0xf, false);
    return fmaxf(__int_as_float(t), v);
}

__device__ __forceinline__ float readlane_f(float v, int lane) {
    return __int_as_float(__builtin_amdgcn_readlane(__float_as_int(v), lane));
}

// packed argmax key: all scores < 0 -> u32-min on raw bits == float-max;
// low 6 bits carry j, tie-break = first occurrence (smaller j).
__device__ __forceinline__ unsigned int pack_key(float a, int j) {
    return (__float_as_uint(a) & 0xFFFFFFC0u) | (unsigned)j;
}

// k1: chunked forward Viterbi, one chain per wave, 4 chains/block.
// strans staged as fp16 (8 KB LDS). Per-block Mc (column-min pruning
// bound): Mc[j] = min_i(rowmin_i - trans[i][j]) <= 0; winner j of any row
// satisfies c_j >= cmax + Mc[j]. Loads-only steady-state vmcnt queue;
// bp bytes packed 4/dword in registers, burst-stored at chunk end.
__global__ __launch_bounds__(256, 8) void k1_forward(
    const int* __restrict__ rolls, const float* __restrict__ trans,
    const float* __restrict__ ll,
    unsigned int* __restrict__ bp4, int* __restrict__ wsFinal,
    float* __restrict__ out_score) {
    __shared__ __half strans_h[S * S];  // strans_h[j*64 + i] = trans[i][j]
    __shared__ float srowmin[S];
    __shared__ float sMc[S];
    const int tid = threadIdx.x;
    const int lane = tid & 63;
    const int wv = tid >> 6;

    if (blockIdx.x == 0 && tid == 0)
        out_score[0] = 0.0f;  // k2 is stream-ordered after k1 -> safe

    for (int k = tid; k < S * S; k += 256)
        strans_h[k] = __float2half(trans[(k & 63) * SP1 + (k >> 6)]);
    __syncthreads();

    // per-block Mc: rowmin_i = min_j trans[i][j]; Mc[j] = min_i(rowmin_i - trans[i][j])
    {
        int i = tid >> 2, q = tid & 3;
        float mn = 3.0e38f;
        #pragma unroll
        for (int u = 0; u < 16; ++u)
            mn = fminf(mn, __half2float(strans_h[((q * 16 + u) << 6) | i]));
        mn = fminf(mn, __shfl_xor(mn, 1));
        mn = fminf(mn, __shfl_xor(mn, 2));
        if (q == 0) srowmin[i] = mn;
    }
    __syncthreads();
    {
        int j = tid >> 2, q = tid & 3;
        float mc = 3.0e38f;
        #pragma unroll
        for (int u = 0; u < 16; ++u) {
            int i = q * 16 + u;
            mc = fminf(mc, srowmin[i] - __half2float(strans_h[(j << 6) | i]));
        }
        mc = fminf(mc, __shfl_xor(mc, 1));
        mc = fminf(mc, __shfl_xor(mc, 2));
        if (q == 0) sMc[j] = mc;
    }
    __syncthreads();
    const float mcol = sMc[lane];

    const int c = blockIdx.x * 4 + wv;
    const int beg_out = c * L_FWD;
    int t0 = beg_out - W_FWD;
    if (t0 < 1) t0 = 1;

    // rolls for the whole chunk (plus prefetch slack) in one VGPR
    int vroll = rolls[min(t0 + lane, T_LEN - 1)];

    float delta;
    if (c == 0) {
        delta = trans[lane * SP1 + S] + ll[rolls[0] * S + lane];  // exact init
    } else {
        delta = 0.0f;  // arbitrary; warm-up coalesces (up to additive const)
    }

    // ll pipeline: ll_cur for step t, ll_nxt for t+1; issue t+2 in-loop
    int r0 = __builtin_amdgcn_readlane(vroll, 0);
    int r1 = __builtin_amdgcn_readlane(vroll, 1);
    float ll_cur = ll[r0 * S + lane];
    float ll_nxt = ll[r1 * S + lane];

    int idx = 0;  // t - t0

    auto step = [&]() -> unsigned int {
        int rp = __builtin_amdgcn_readlane(vroll, idx + 2);
        float ll_new = ll[rp * S + lane];  // used at t+2

        float cvec = delta + ll_cur;  // < 0 always

        // exact wave-wide max via fused dpp fmax chain
        float mxc = cvec;
        mxc = dpp_fmax_step<0x111>(mxc);
        mxc = dpp_fmax_step<0x112>(mxc);
        mxc = dpp_fmax_step<0x114>(mxc);
        mxc = dpp_fmax_step<0x118>(mxc);
        mxc = dpp_fmax_step<0x142>(mxc);
        mxc = dpp_fmax_step<0x143>(mxc);
        float cmax = readlane_f(mxc, 63);

        // exact per-lane pruning: survivors satisfy c_j >= cmax + Mc[j];
        // argmax lane always present (Mc <= 0)
        float thr = cmax + mcol;
        unsigned long long mask = __ballot(cvec >= thr);

        int j0 = __ffsll(mask) - 1;
        unsigned long long rm = mask & (mask - 1);
        int j1 = rm ? (__ffsll(rm) - 1) : j0;
        float a0 = __half2float(strans_h[(j0 << 6) | lane]) + readlane_f(cvec, j0);
        float a1 = __half2float(strans_h[(j1 << 6) | lane]) + readlane_f(cvec, j1);
        unsigned int m = min(pack_key(a0, j0), pack_key(a1, j1));

        unsigned long long rest = rm ? (rm & (rm - 1)) : 0ull;
        if (rest) {  // wave-uniform scalar branch; ~1/3 of steps
            int j2 = __ffsll(rest) - 1;
            unsigned long long r3 = rest & (rest - 1);
            int j3 = r3 ? (__ffsll(r3) - 1) : j2;
            float a2 = __half2float(strans_h[(j2 << 6) | lane]) + readlane_f(cvec, j2);
            float a3 = __half2float(strans_h[(j3 << 6) | lane]) + readlane_f(cvec, j3);
            m = min(m, min(pack_key(a2, j2), pack_key(a3, j3)));
            rest = r3 ? (r3 & (r3 - 1)) : 0ull;
            while (rest) {  // rare (>4 survivors)
                int j = __ffsll(rest) - 1;
                rest &= (rest - 1);
                float a = __half2float(strans_h[(j << 6) | lane]) + readlane_f(cvec, j);
                m = min(m, pack_key(a, j));
            }
        }

        delta = __uint_as_float(m & 0xFFFFFFC0u);  // quantized (~2^-15 rel)
        ll_cur = ll_nxt;
        ll_nxt = ll_new;
        ++idx;
        return m;
    };

    // warm-up: exactly W_FWD steps for c>0 (c==0 starts exact at t=1)
    if (c != 0) {
        #pragma unroll
        for (int w = 0; w < W_FWD; ++w)
            (void)step();
    }

    // main: 8 packed dwords accumulated in registers; burst store at end
    const int qb = beg_out >> 2;
    unsigned int pk[8];
    {   // q = 0: c==0 covers t=1..3 only (byte 0 never read by backtrack)
        unsigned int p = 0u;
        int u0 = (c == 0) ? 1 : 0;
        for (int u = u0; u < 4; ++u) {
            unsigned int m = step();
            p = (p >> 8) | ((m & 63u) << 24);
        }
        pk[0] = p;
    }
    #pragma unroll
    for (int q = 1; q < 8; ++q) {
        unsigned int p = 0u;
        #pragma unroll
        for (int u = 0; u < 4; ++u) {
            unsigned int m = step();
            p = (p >> 8) | ((m & 63u) << 24);
        }
        pk[q] = p;
    }
    #pragma unroll
    for (int q = 0; q < 8; ++q)
        bp4[(unsigned)((qb + q) << 6) | (unsigned)lane] = pk[q];

    if (c == C_FWD - 1) {
        float fmx = delta;
        for (int off = 32; off; off >>= 1)
            fmx = fmaxf(fmx, __shfl_xor(fmx, off));
        unsigned long long em = __ballot(delta == fmx);
        if (lane == 0)
            *wsFinal = __ffsll(em) - 1;
    }
}

// k2: one THREAD per window. Chase 15 dependent gathers from te=thi+VB2
// (single seed; bp columns concentrate on ~2 survivors so backward chains
// coalesce inside VB2=8), record s[tlo..thi+1] in LDS, write the path,
// then score own window with neighbor-stitched boundary; one atomic/block.
// Scoring uses fp32 tables -> returned score is exact for the emitted path.
__global__ __launch_bounds__(256) void k2_backtrack(
    const unsigned int* __restrict__ bp4, const int* __restrict__ wsFinal,
    const int* __restrict__ rolls, const float* __restrict__ trans,
    const float* __restrict__ ll, float* __restrict__ out_path,
    float* __restrict__ out_score) {
    __shared__ int sst[256 * PITCH];
    __shared__ float spart[4];
    const int tid = threadIdx.x;
    const int b = blockIdx.x * 256 + tid;   // window id
    const int tlo = b * LB2;
    const int thi = tlo + LB2 - 1;
    int te = thi + VB2;
    int s;
    if (te >= T_LEN - 1) {
        te = T_LEN - 1;
        s = *wsFinal;   // exact seed for the tail windows
    } else {
        s = 0;          // arbitrary; chase coalesces
    }
    int* row = sst + tid * PITCH;
    #pragma unroll
    for (int u = 0; u < LB2 + VB2 - 1; ++u) {  // 15 dependent gathers max
        int t = te - u;
        if (t > tlo) {
            if (t <= thi + 1) row[t - tlo] = s;
            unsigned int w = bp4[((unsigned)(t >> 2) << 6) | (unsigned)s];
            s = (int)((w >> ((t & 3) << 3)) & 63u);
        }
    }
    row[0] = s;  // state at tlo
    __syncthreads();

    // path write: out[T-1-t] = s_t for t in [tlo, thi]
    #pragma unroll
    for (int u = 0; u < LB2; ++u)
        out_path[T_LEN - 1 - (tlo + u)] = (float)row[u];

    // score terms: t in [tlo+1, thi+1] (clamped to T-1):
    //   trans[s_t][s_{t-1}] + ll[rolls[t]][s_{t-1}]
    float acc = 0.0f;
    #pragma unroll
    for (int u = 1; u <= LB2; ++u) {
        int t = tlo + u;
        if (t <= T_LEN - 1) {
            int sp = row[u - 1];
            int st = (u == LB2)
                         ? ((tid < 255) ? sst[(tid + 1) * PITCH] : row[LB2])
                         : row[u];
            acc += trans[st * SP1 + sp] + ll[rolls[t] * S + sp];
        }
    }
    if (b == 0) {  // init term
        int s0 = row[0];
        acc += trans[s0 * SP1 + S] + ll[rolls[0] * S + s0];
    }

    for (int off = 32; off; off >>= 1)
        acc += __shfl_xor(acc, off);
    if ((tid & 63) == 0) spart[tid >> 6] = acc;
    __syncthreads();
    if (tid == 0)
        atomicAdd(out_score, (spart[0] + spart[1]) + (spart[2] + spart[3]));
}

extern "C" void kernel_launch(void* const* d_in, const int* in_sizes, int n_in,
                              void* d_out, int out_size, void* d_ws, size_t ws_size,
                              hipStream_t stream) {
    const int* rolls = (const int*)d_in[0];
    const float* trans = (const float*)d_in[1];   // (64, 65)
    const float* ll = (const float*)d_in[2];      // (128, 64)
    float* out = (float*)d_out;                   // [0..T): path (reverse), [T]: score
    char* ws = (char*)d_ws;
    int* wsFinal = (int*)(ws + 8);
    unsigned int* bp4 = (unsigned int*)(ws + 2048); // 16 MiB packed bp

    k1_forward<<<C_FWD / 4, 256, 0, stream>>>(rolls, trans, ll, bp4, wsFinal,
                                              out + T_LEN);
    k2_backtrack<<<NW / 256, 256, 0, stream>>>(bp4, wsFinal, rolls, trans, ll,
                                               out, out + T_LEN);
}